// Round 1
// baseline (612.195 us; speedup 1.0000x reference)
//
#include <hip/hip_runtime.h>
#include <hip/hip_bf16.h>

#define B_ 16
#define C_ 256
#define O_ 256
#define P_ 3136
#define E_ 8
#define HID_ 512
#define EPS_ 1e-5f

typedef __attribute__((ext_vector_type(8))) short bf16x8;
typedef __attribute__((ext_vector_type(4))) float f32x4;
typedef __hip_bfloat16 bf16;

__device__ __forceinline__ void gl2lds16(const bf16* g, bf16* l) {
  __builtin_amdgcn_global_load_lds((const __attribute__((address_space(1))) void*)g,
                                   (__attribute__((address_space(3))) void*)l,
                                   16, 0, 0);
}

// ---------------- prep: x NCHW fp32 -> NHWC bf16 ----------------
__global__ __launch_bounds__(256) void xT_kernel(const float* __restrict__ x,
                                                 bf16* __restrict__ xT) {
  __shared__ float tile[64][65];
  const int p0 = blockIdx.x * 64, c0 = blockIdx.y * 64, b = blockIdx.z;
  const int t = threadIdx.x;
#pragma unroll
  for (int j = 0; j < 16; ++j) {
    int idx = t + j * 256;
    int cl = idx >> 6, pl = idx & 63;
    tile[cl][pl] = x[(size_t)(b * C_ + c0 + cl) * P_ + p0 + pl];
  }
  __syncthreads();
#pragma unroll
  for (int j = 0; j < 16; ++j) {
    int idx = t + j * 256;
    int pl = idx >> 6, cl = idx & 63;
    xT[(size_t)(b * P_ + p0 + pl) * C_ + c0 + cl] = __float2bfloat16(tile[cl][pl]);
  }
}

// ---------------- prep: w1 [E][HID][C][3][3] -> [E][9][HID][C] bf16, BN1 scale folded ----
__global__ __launch_bounds__(256) void w1cvt_kernel(const float* __restrict__ w1,
                                                    const float* __restrict__ bn1_scale,
                                                    bf16* __restrict__ w1b) {
  const int eh = blockIdx.x;           // e*HID + hid
  const int e = eh >> 9, hid = eh & 511;
  __shared__ float buf[2304];
  const float* src = w1 + (size_t)eh * 2304;
  const int t = threadIdx.x;
  for (int i = t; i < 2304; i += 256) buf[i] = src[i];
  __syncthreads();
  const float inv = bn1_scale[eh] * (1.0f / sqrtf(1.0f + EPS_));
  for (int i = t; i < 2304; i += 256) {
    int rs = i >> 8, c = i & 255;
    w1b[((size_t)(e * 9 + rs) * HID_ + hid) * C_ + c] = __float2bfloat16(buf[c * 9 + rs] * inv);
  }
}

// ---------------- prep: w2 -> bf16 with BN2 scale folded ----------------
__global__ __launch_bounds__(256) void w2cvt_kernel(const float* __restrict__ w2,
                                                    const float* __restrict__ bn2_scale,
                                                    bf16* __restrict__ w2b) {
  const int i = blockIdx.x * 256 + threadIdx.x;   // E*O*HID = 1048576
  const int eo = i >> 9;
  w2b[i] = __float2bfloat16(w2[i] * (bn2_scale[eo] * (1.0f / sqrtf(1.0f + EPS_))));
}

// ---------------- prep: shared_w -> bf16 with BN scale folded ----------------
__global__ __launch_bounds__(256) void wshcvt_kernel(const float* __restrict__ wsh,
                                                     const float* __restrict__ sscale,
                                                     bf16* __restrict__ wshb) {
  const int i = blockIdx.x * 256 + threadIdx.x;   // O*C = 65536
  wshb[i] = __float2bfloat16(wsh[i] * (sscale[i >> 8] * (1.0f / sqrtf(1.0f + EPS_))));
}

// ---------------- router stage 1: global average pool ----------------
__global__ __launch_bounds__(256) void pooled_kernel(const float* __restrict__ x,
                                                     float* __restrict__ pooled) {
  const int row = blockIdx.x;                     // b*C + c
  const float* p = x + (size_t)row * P_;
  float s = 0.f;
  for (int i = threadIdx.x; i < P_; i += 256) s += p[i];
#pragma unroll
  for (int off = 32; off; off >>= 1) s += __shfl_down(s, off);
  __shared__ float ws4[4];
  if ((threadIdx.x & 63) == 0) ws4[threadIdx.x >> 6] = s;
  __syncthreads();
  if (threadIdx.x == 0) pooled[row] = (ws4[0] + ws4[1] + ws4[2] + ws4[3]) * (1.0f / P_);
}

// ---------------- router stage 2: logits/softmax/top2 + gated bias sums ----------------
__global__ __launch_bounds__(256) void router_kernel(const float* __restrict__ pooled,
                                                     const float* __restrict__ rw,
                                                     const float* __restrict__ rb,
                                                     const float* __restrict__ bn2_bias,
                                                     int* __restrict__ ridx,
                                                     float* __restrict__ rwt,
                                                     float* __restrict__ bsum) {
  __shared__ float lp[B_ * C_];
  __shared__ float llog[B_ * E_];
  __shared__ int lidx[B_ * 2];
  __shared__ float lw[B_ * 2];
  const int t = threadIdx.x;
  for (int i = t; i < B_ * C_; i += 256) lp[i] = pooled[i];
  __syncthreads();
  if (t < B_ * E_) {
    int b = t >> 3, e = t & 7;
    float s = rb[e];
    for (int c = 0; c < C_; ++c) s += lp[b * C_ + c] * rw[e * C_ + c];
    llog[t] = s;
  }
  __syncthreads();
  if (t < B_) {
    float pr[E_];
    float m = -1e30f;
    for (int e = 0; e < E_; ++e) { pr[e] = llog[t * E_ + e]; m = fmaxf(m, pr[e]); }
    float s = 0.f;
    for (int e = 0; e < E_; ++e) { pr[e] = __expf(pr[e] - m); s += pr[e]; }
    const float is = 1.f / s;
    for (int e = 0; e < E_; ++e) pr[e] *= is;
    int i0 = 0; float v0 = pr[0];
    for (int e = 1; e < E_; ++e) if (pr[e] > v0) { v0 = pr[e]; i0 = e; }
    int i1 = -1; float v1 = -1.f;
    for (int e = 0; e < E_; ++e) if (e != i0 && pr[e] > v1) { v1 = pr[e]; i1 = e; }
    const float wsum = 1.f / (v0 + v1);
    ridx[t * 2] = i0; ridx[t * 2 + 1] = i1;
    rwt[t * 2] = v0 * wsum; rwt[t * 2 + 1] = v1 * wsum;
    lidx[t * 2] = i0; lidx[t * 2 + 1] = i1;
    lw[t * 2] = v0 * wsum; lw[t * 2 + 1] = v1 * wsum;
  }
  __syncthreads();
  for (int i = t; i < B_ * O_; i += 256) {
    int b = i >> 8, o = i & 255;
    bsum[i] = lw[b * 2] * bn2_bias[lidx[b * 2] * O_ + o]
            + lw[b * 2 + 1] * bn2_bias[lidx[b * 2 + 1] * O_ + o];
  }
}

// ---------------- conv3x3 C->HID per routed (b,slot), implicit GEMM ----------------
// M = 112 pixels, N = 128 hid, K = 32-chunks over 9 taps x 256 channels.
// h[bs][p][hid] = gate * silu(conv + bn1_bias), bf16.
__global__ __launch_bounds__(256) void conv1_kernel(
    const bf16* __restrict__ xT, const bf16* __restrict__ w1b,
    const float* __restrict__ bn1_bias, const int* __restrict__ ridx,
    const float* __restrict__ rwt, const bf16* __restrict__ zp,
    bf16* __restrict__ h) {
  __shared__ __align__(16) bf16 ldsA[112 * 32];
  __shared__ __align__(16) bf16 ldsB[128 * 32];
  const int t = threadIdx.x;
  const int p0 = blockIdx.x * 112;
  const int h0 = blockIdx.y * 128;
  const int bs = blockIdx.z;
  const int b = bs >> 1;
  const int e = ridx[bs];
  const float wk = rwt[bs];

  const int lane = t & 63, wv = t >> 6;
  const int koff = (lane >> 4) * 8;
  const int r16 = lane & 15;

  const int rA0 = t >> 2;        // staging row, round 1 (0..63)
  const int rA1 = rA0 + 64;      // round 2 (64..111), t<192 only
  const int cA = (t & 3) * 8;
  const int pA0 = p0 + rA0;
  const int pA1 = p0 + rA1;
  const int yA0 = pA0 / 56, xA0 = pA0 % 56;
  const int yA1 = pA1 / 56, xA1 = pA1 % 56;

  f32x4 acc[7][2] = {};

  for (int rs = 0; rs < 9; ++rs) {
    const int dr = rs / 3 - 1, ds = rs % 3 - 1;
    const int off = dr * 56 + ds;
    const bool v0 = ((unsigned)(yA0 + dr) < 56u) & ((unsigned)(xA0 + ds) < 56u);
    const bool v1 = ((unsigned)(yA1 + dr) < 56u) & ((unsigned)(xA1 + ds) < 56u);
    const bf16* sA0 = v0 ? xT + (size_t)(b * P_ + pA0 + off) * C_ + cA : zp + cA;
    const bf16* sA1 = v1 ? xT + (size_t)(b * P_ + pA1 + off) * C_ + cA : zp + cA;
    const bf16* sB = w1b + (size_t)((e * 9 + rs) * HID_ + h0 + rA0) * C_ + cA;

    for (int c0 = 0; c0 < C_; c0 += 32) {
      gl2lds16(sA0 + c0, ldsA + t * 8);
      if (t < 192) gl2lds16(sA1 + c0, ldsA + (t + 256) * 8);
      gl2lds16(sB + c0, ldsB + t * 8);
      gl2lds16(sB + 64 * C_ + c0, ldsB + (t + 256) * 8);
      __syncthreads();
      bf16x8 bf0 = *(const bf16x8*)(ldsB + (wv * 32 + r16) * 32 + koff);
      bf16x8 bf1 = *(const bf16x8*)(ldsB + (wv * 32 + 16 + r16) * 32 + koff);
#pragma unroll
      for (int mi = 0; mi < 7; ++mi) {
        bf16x8 af = *(const bf16x8*)(ldsA + (mi * 16 + r16) * 32 + koff);
        acc[mi][0] = __builtin_amdgcn_mfma_f32_16x16x32_bf16(af, bf0, acc[mi][0], 0, 0, 0);
        acc[mi][1] = __builtin_amdgcn_mfma_f32_16x16x32_bf16(af, bf1, acc[mi][1], 0, 0, 0);
      }
      __syncthreads();
    }
  }

  const int rowq = (lane >> 4) * 4;
#pragma unroll
  for (int ni = 0; ni < 2; ++ni) {
    const int hid = h0 + wv * 32 + ni * 16 + r16;
    const float bias = bn1_bias[e * HID_ + hid];
#pragma unroll
    for (int mi = 0; mi < 7; ++mi) {
#pragma unroll
      for (int i = 0; i < 4; ++i) {
        const int p = p0 + mi * 16 + rowq + i;
        float v = acc[mi][ni][i] + bias;
        v = v / (1.f + __expf(-v));
        h[((size_t)bs * P_ + p) * HID_ + hid] = __float2bfloat16(wk * v);
      }
    }
  }
}

// ---------------- combine: shared 1x1 (SiLU) + both experts' 1x1 + bias + residual ----
// M = 128 o, N = 112 pixels.
__global__ __launch_bounds__(256) void combine_kernel(
    const bf16* __restrict__ xT, const bf16* __restrict__ h,
    const bf16* __restrict__ wshb, const bf16* __restrict__ w2b,
    const float* __restrict__ sbias, const float* __restrict__ bsum,
    const int* __restrict__ ridx, const float* __restrict__ x,
    float* __restrict__ out) {
  __shared__ __align__(16) bf16 ldsA[128 * 32];
  __shared__ __align__(16) bf16 ldsB[112 * 32];
  const int t = threadIdx.x;
  const int p0 = blockIdx.x * 112;
  const int o0 = blockIdx.y * 128;
  const int b = blockIdx.z;
  const int lane = t & 63, wv = t >> 6;
  const int koff = (lane >> 4) * 8;
  const int r16 = lane & 15;
  const int rT = t >> 2;
  const int cT = (t & 3) * 8;

  f32x4 acc[2][7] = {};
  f32x4 res[2][7];

  // phase 1: shared expert, K = C_
  {
    const bf16* sA = wshb + (size_t)(o0 + rT) * C_ + cT;
    const bf16* sB = xT + (size_t)(b * P_ + p0 + rT) * C_ + cT;
    for (int c0 = 0; c0 < C_; c0 += 32) {
      gl2lds16(sA + c0, ldsA + t * 8);
      gl2lds16(sA + 64 * C_ + c0, ldsA + (t + 256) * 8);
      gl2lds16(sB + c0, ldsB + t * 8);
      if (t < 192) gl2lds16(sB + 64 * C_ + c0, ldsB + (t + 256) * 8);
      __syncthreads();
      bf16x8 a0 = *(const bf16x8*)(ldsA + (wv * 32 + r16) * 32 + koff);
      bf16x8 a1 = *(const bf16x8*)(ldsA + (wv * 32 + 16 + r16) * 32 + koff);
#pragma unroll
      for (int ni = 0; ni < 7; ++ni) {
        bf16x8 bf = *(const bf16x8*)(ldsB + (ni * 16 + r16) * 32 + koff);
        acc[0][ni] = __builtin_amdgcn_mfma_f32_16x16x32_bf16(a0, bf, acc[0][ni], 0, 0, 0);
        acc[1][ni] = __builtin_amdgcn_mfma_f32_16x16x32_bf16(a1, bf, acc[1][ni], 0, 0, 0);
      }
      __syncthreads();
    }
  }
  const int rowq = (lane >> 4) * 4;
#pragma unroll
  for (int mi = 0; mi < 2; ++mi) {
    const int ob = o0 + wv * 32 + mi * 16 + rowq;
#pragma unroll
    for (int i = 0; i < 4; ++i) {
      const float bias = sbias[ob + i];
#pragma unroll
      for (int ni = 0; ni < 7; ++ni) {
        float v = acc[mi][ni][i] + bias;
        res[mi][ni][i] = v / (1.f + __expf(-v));
        acc[mi][ni][i] = 0.f;
      }
    }
  }
  // phase 2: two routed experts accumulated into one acc (gate folded into h)
  for (int slot = 0; slot < 2; ++slot) {
    const int e = ridx[b * 2 + slot];
    const bf16* sA = w2b + (size_t)(e * O_ + o0 + rT) * HID_ + cT;
    const bf16* sB = h + (size_t)((b * 2 + slot) * P_ + p0 + rT) * HID_ + cT;
    for (int c0 = 0; c0 < HID_; c0 += 32) {
      gl2lds16(sA + c0, ldsA + t * 8);
      gl2lds16(sA + 64 * HID_ + c0, ldsA + (t + 256) * 8);
      gl2lds16(sB + c0, ldsB + t * 8);
      if (t < 192) gl2lds16(sB + 64 * HID_ + c0, ldsB + (t + 256) * 8);
      __syncthreads();
      bf16x8 a0 = *(const bf16x8*)(ldsA + (wv * 32 + r16) * 32 + koff);
      bf16x8 a1 = *(const bf16x8*)(ldsA + (wv * 32 + 16 + r16) * 32 + koff);
#pragma unroll
      for (int ni = 0; ni < 7; ++ni) {
        bf16x8 bf = *(const bf16x8*)(ldsB + (ni * 16 + r16) * 32 + koff);
        acc[0][ni] = __builtin_amdgcn_mfma_f32_16x16x32_bf16(a0, bf, acc[0][ni], 0, 0, 0);
        acc[1][ni] = __builtin_amdgcn_mfma_f32_16x16x32_bf16(a1, bf, acc[1][ni], 0, 0, 0);
      }
      __syncthreads();
    }
  }
  // epilogue: res(silu shared) + expert acc + gated bn2 bias + residual x
#pragma unroll
  for (int mi = 0; mi < 2; ++mi) {
    const int ob = o0 + wv * 32 + mi * 16 + rowq;
#pragma unroll
    for (int i = 0; i < 4; ++i) {
      const int o = ob + i;
      const float bb = bsum[b * O_ + o];
      const size_t orow = (size_t)(b * O_ + o) * P_;
#pragma unroll
      for (int ni = 0; ni < 7; ++ni) {
        const int p = p0 + ni * 16 + r16;
        out[orow + p] = res[mi][ni][i] + acc[mi][ni][i] + bb + x[orow + p];
      }
    }
  }
}

// ---------------- workspace layout ----------------
constexpr size_t SZ_XT = (size_t)B_ * P_ * C_ * 2;
constexpr size_t SZ_W1B = (size_t)E_ * 9 * HID_ * C_ * 2;
constexpr size_t SZ_W2B = (size_t)E_ * O_ * HID_ * 2;
constexpr size_t SZ_WSHB = (size_t)O_ * C_ * 2;
constexpr size_t SZ_POOL = (size_t)B_ * C_ * 4;
constexpr size_t SZ_BSUM = (size_t)B_ * O_ * 4;
constexpr size_t SZ_H = (size_t)B_ * 2 * P_ * HID_ * 2;

constexpr size_t OFF_XT = 0;
constexpr size_t OFF_W1B = OFF_XT + SZ_XT;
constexpr size_t OFF_W2B = OFF_W1B + SZ_W1B;
constexpr size_t OFF_WSHB = OFF_W2B + SZ_W2B;
constexpr size_t OFF_POOL = OFF_WSHB + SZ_WSHB;
constexpr size_t OFF_RIDX = OFF_POOL + SZ_POOL;   // 128 B
constexpr size_t OFF_RWT = OFF_RIDX + 128;        // 128 B
constexpr size_t OFF_BSUM = OFF_RWT + 128;
constexpr size_t OFF_ZERO = OFF_BSUM + SZ_BSUM;   // 1024 B zero page
constexpr size_t OFF_H = OFF_ZERO + 1024;

extern "C" void kernel_launch(void* const* d_in, const int* in_sizes, int n_in,
                              void* d_out, int out_size, void* d_ws, size_t ws_size,
                              hipStream_t stream) {
  const float* x = (const float*)d_in[0];
  const float* router_w = (const float*)d_in[1];
  const float* router_b = (const float*)d_in[2];
  const float* shared_w = (const float*)d_in[3];
  const float* shared_scale = (const float*)d_in[4];
  const float* shared_bias = (const float*)d_in[5];
  const float* w1 = (const float*)d_in[6];
  const float* bn1_scale = (const float*)d_in[7];
  const float* bn1_bias = (const float*)d_in[8];
  const float* w2 = (const float*)d_in[9];
  const float* bn2_scale = (const float*)d_in[10];
  const float* bn2_bias = (const float*)d_in[11];
  float* out = (float*)d_out;
  char* ws = (char*)d_ws;

  bf16* xT = (bf16*)(ws + OFF_XT);
  bf16* w1b = (bf16*)(ws + OFF_W1B);
  bf16* w2b = (bf16*)(ws + OFF_W2B);
  bf16* wshb = (bf16*)(ws + OFF_WSHB);
  float* pooled = (float*)(ws + OFF_POOL);
  int* ridx = (int*)(ws + OFF_RIDX);
  float* rwt = (float*)(ws + OFF_RWT);
  float* bsum = (float*)(ws + OFF_BSUM);
  bf16* zp = (bf16*)(ws + OFF_ZERO);
  bf16* h = (bf16*)(ws + OFF_H);

  hipMemsetAsync(ws + OFF_ZERO, 0, 1024, stream);

  xT_kernel<<<dim3(49, 4, 16), 256, 0, stream>>>(x, xT);
  w1cvt_kernel<<<E_ * HID_, 256, 0, stream>>>(w1, bn1_scale, w1b);
  w2cvt_kernel<<<(E_ * O_ * HID_) / 256, 256, 0, stream>>>(w2, bn2_scale, w2b);
  wshcvt_kernel<<<(O_ * C_) / 256, 256, 0, stream>>>(shared_w, shared_scale, wshb);
  pooled_kernel<<<B_ * C_, 256, 0, stream>>>(x, pooled);
  router_kernel<<<1, 256, 0, stream>>>(pooled, router_w, router_b, bn2_bias, ridx, rwt, bsum);
  conv1_kernel<<<dim3(28, 4, 32), 256, 0, stream>>>(xT, w1b, bn1_bias, ridx, rwt, zp, h);
  combine_kernel<<<dim3(28, 2, 16), 256, 0, stream>>>(xT, h, wshb, w2b, shared_bias, bsum, ridx, x, out);
}